// Round 1
// baseline (687.248 us; speedup 1.0000x reference)
//
#include <hip/hip_runtime.h>
#include <hip/hip_bf16.h>
#include <stdint.h>

typedef unsigned short u16;
typedef __attribute__((ext_vector_type(8))) short s8v;   // 8 bf16 (4 VGPRs)
typedef __attribute__((ext_vector_type(4))) float f4v;   // 4 fp32

#define SQ   2048
#define HDIM 2048
#define HD_  128
#define NH_  16
#define NKV_ 8

__device__ __forceinline__ u16 f2b(float f) {
  uint32_t u = __builtin_bit_cast(uint32_t, f);
  u += 0x7fffu + ((u >> 16) & 1u);
  return (u16)(u >> 16);
}
__device__ __forceinline__ float b2f(u16 v) {
  uint32_t u = ((uint32_t)v) << 16;
  return __builtin_bit_cast(float, u);
}

// ---------------- cast f32 -> bf16, 4 elems/thread ----------------
__global__ __launch_bounds__(256) void k_cast(const float* __restrict__ in,
                                              u16* __restrict__ out, int n4) {
  int i = blockIdx.x * 256 + threadIdx.x;
  if (i >= n4) return;
  f4v v = *(const f4v*)(in + (size_t)i * 4);
  union { u16 s[4]; uint64_t u; } o;
  o.s[0] = f2b(v[0]); o.s[1] = f2b(v[1]); o.s[2] = f2b(v[2]); o.s[3] = f2b(v[3]);
  *(uint64_t*)(out + (size_t)i * 4) = o.u;
}

// ---------------- transpose + cast: in (rows x cols) f32 -> out (cols x rows) bf16 ----------------
__global__ __launch_bounds__(256) void k_transpose_cast(const float* __restrict__ in,
                                                        u16* __restrict__ out,
                                                        int rows, int cols) {
  __shared__ float tile[32][33];
  int tx = threadIdx.x, ty = threadIdx.y;
  int c0 = blockIdx.x * 32, r0 = blockIdx.y * 32;
#pragma unroll
  for (int i = 0; i < 32; i += 8)
    tile[ty + i][tx] = in[(size_t)(r0 + ty + i) * cols + c0 + tx];
  __syncthreads();
#pragma unroll
  for (int i = 0; i < 32; i += 8)
    out[(size_t)(c0 + ty + i) * rows + r0 + tx] = f2b(tile[tx][ty + i]);
}

// ---------------- bf16 GEMM: C[M,N] = A[M,K] * Bt[N,K]^T ----------------
// 128x128 tile, BK=64, 4 waves (2x2), wave tile 64x64, 16x16x32 MFMA.
// LDS XOR-swizzle: byte ^= ((row&7)<<4) within each 128B row.
template <int F32OUT>
__global__ __launch_bounds__(256) void k_gemm(const u16* __restrict__ A,
                                              const u16* __restrict__ Bt,
                                              void* __restrict__ C,
                                              int M, int N, int K) {
  __shared__ u16 As[128 * 64];
  __shared__ u16 Bs[128 * 64];
  const int tid = threadIdx.x;
  const int lane = tid & 63, wvi = tid >> 6;
  const int wm = wvi >> 1, wn = wvi & 1;
  const int l15 = lane & 15, l4 = lane >> 4;
  const int m0 = blockIdx.y * 128, n0 = blockIdx.x * 128;
  f4v acc[4][4] = {};
  for (int k0 = 0; k0 < K; k0 += 64) {
#pragma unroll
    for (int i = 0; i < 4; i++) {
      int ci = i * 256 + tid;
      int r  = ci >> 3;
      int cb = (ci & 7) * 16;
      int sw = cb ^ ((r & 7) << 4);
      *(f4v*)((char*)As + r * 128 + sw) =
          *(const f4v*)((const char*)(A + (size_t)(m0 + r) * K + k0) + cb);
      *(f4v*)((char*)Bs + r * 128 + sw) =
          *(const f4v*)((const char*)(Bt + (size_t)(n0 + r) * K + k0) + cb);
    }
    __syncthreads();
#pragma unroll
    for (int kk = 0; kk < 2; kk++) {
      s8v af[4], bf[4];
#pragma unroll
      for (int i = 0; i < 4; i++) {
        int ra = wm * 64 + i * 16 + l15;
        af[i] = *(const s8v*)((const char*)As + ra * 128 +
                              ((kk * 64 + l4 * 16) ^ ((ra & 7) << 4)));
        int rb = wn * 64 + i * 16 + l15;
        bf[i] = *(const s8v*)((const char*)Bs + rb * 128 +
                              ((kk * 64 + l4 * 16) ^ ((rb & 7) << 4)));
      }
#pragma unroll
      for (int i = 0; i < 4; i++)
#pragma unroll
        for (int j = 0; j < 4; j++)
          acc[i][j] = __builtin_amdgcn_mfma_f32_16x16x32_bf16(af[i], bf[j], acc[i][j], 0, 0, 0);
    }
    __syncthreads();
  }
  // epilogue: D row = (lane>>4)*4 + reg, col = lane&15  [measured m89]
#pragma unroll
  for (int i = 0; i < 4; i++) {
#pragma unroll
    for (int j = 0; j < 4; j++) {
      int mb = m0 + wm * 64 + i * 16 + l4 * 4;
      int nn = n0 + wn * 64 + j * 16 + l15;
#pragma unroll
      for (int r = 0; r < 4; r++) {
        float v = acc[i][j][r];
        if (F32OUT) ((float*)C)[(size_t)(mb + r) * N + nn] = v;
        else        ((u16*)C)[(size_t)(mb + r) * N + nn]  = f2b(v);
      }
    }
  }
}

// ---------------- RMSNorm + RoPE + layout repack ----------------
// q_raw row layout: col = d*16 + h ; k_raw/v_raw: col = d*8 + kv
// outputs: qq[b,h,s,d] (q also scaled by 1/sqrt(HD)), kk[b,kv,s,d], vt[b,kv,d,s]
__global__ __launch_bounds__(256) void k_normrope(const u16* __restrict__ q_raw,
                                                  const u16* __restrict__ k_raw,
                                                  const u16* __restrict__ v_raw,
                                                  const float* __restrict__ rms_w,
                                                  const int* __restrict__ pos_arr,
                                                  u16* __restrict__ qq,
                                                  u16* __restrict__ kko,
                                                  u16* __restrict__ vto) {
  int idx = blockIdx.x;            // b*SQ + s
  int b = idx >> 11, s = idx & 2047;
  int t = threadIdx.x;
  __shared__ float part[256];
  __shared__ float rstdq[16], rstdk[8];
  __shared__ float lcos[64], lsin[64];
  float pos = (float)pos_arr[s];
  if (t < 64) {
    // inv_freq[i] = 10000^(-i/64) = exp2(-i * log2(10000)/64)
    float ang = pos * exp2f(-0.20762050593046f * (float)t);
    float sn, cs;
    sincosf(ang, &sn, &cs);
    lcos[t] = cs; lsin[t] = sn;
  }
  // ---- Q ----
  const u16* qr = q_raw + (size_t)idx * 2048;
  int h = t & 15, ch = t >> 4;
  float qv[8]; float ss = 0.f;
#pragma unroll
  for (int j = 0; j < 8; j++) {
    float v = b2f(qr[(ch * 8 + j) * 16 + h]);
    qv[j] = v; ss += v * v;
  }
  part[t] = ss;
  __syncthreads();
  if (t < 16) {
    float tot = 0.f;
#pragma unroll
    for (int c = 0; c < 16; c++) tot += part[c * 16 + t];
    rstdq[t] = rsqrtf(tot * (1.f / 128.f) + 1e-6f);
  }
  __syncthreads();
  {
    float rs = rstdq[h];
    s8v ov;
#pragma unroll
    for (int p = 0; p < 4; p++) {
      int d0 = ch * 8 + p * 2;
      float v0 = qv[p * 2]     * rs * rms_w[d0];
      float v1 = qv[p * 2 + 1] * rs * rms_w[d0 + 1];
      float cs = lcos[d0 >> 1], sn = lsin[d0 >> 1];
      ov[p * 2]     = (short)f2b((v0 * cs - v1 * sn) * 0.08838834764831845f);
      ov[p * 2 + 1] = (short)f2b((v0 * sn + v1 * cs) * 0.08838834764831845f);
    }
    *(s8v*)(qq + ((size_t)(b * 16 + h) * SQ + s) * HD_ + ch * 8) = ov;
  }
  __syncthreads();
  // ---- K (threads < 128) ----
  const u16* kr = k_raw + (size_t)idx * 1024;
  const u16* vr = v_raw + (size_t)idx * 1024;
  int kv = t & 7, ch2 = t >> 3;
  float kvs[8]; float ssk = 0.f;
  if (t < 128) {
#pragma unroll
    for (int j = 0; j < 8; j++) {
      float v = b2f(kr[(ch2 * 8 + j) * 8 + kv]);
      kvs[j] = v; ssk += v * v;
    }
    part[t] = ssk;
  }
  __syncthreads();
  if (t < 8) {
    float tot = 0.f;
#pragma unroll
    for (int c = 0; c < 16; c++) tot += part[c * 8 + t];
    rstdk[t] = rsqrtf(tot * (1.f / 128.f) + 1e-6f);
  }
  __syncthreads();
  if (t < 128) {
    float rs = rstdk[kv];
    s8v ov;
#pragma unroll
    for (int p = 0; p < 4; p++) {
      int d0 = ch2 * 8 + p * 2;
      float v0 = kvs[p * 2]     * rs * rms_w[d0];
      float v1 = kvs[p * 2 + 1] * rs * rms_w[d0 + 1];
      float cs = lcos[d0 >> 1], sn = lsin[d0 >> 1];
      ov[p * 2]     = (short)f2b(v0 * cs - v1 * sn);
      ov[p * 2 + 1] = (short)f2b(v0 * sn + v1 * cs);
    }
    *(s8v*)(kko + ((size_t)(b * 8 + kv) * SQ + s) * HD_ + ch2 * 8) = ov;
    // V transpose: vt[b,kv,d,s]
#pragma unroll
    for (int j = 0; j < 8; j++) {
      int d = ch2 * 8 + j;
      vto[((size_t)(b * 8 + kv) * HD_ + d) * SQ + s] = vr[d * 8 + kv];
    }
  }
}

// ---------------- causal flash attention ----------------
// grid (S/64, NH, B); 256 threads = 4 waves, wave w owns q rows s0+16w..+15.
__global__ __launch_bounds__(256) void k_attn(const u16* __restrict__ qq,
                                              const u16* __restrict__ kk,
                                              const u16* __restrict__ vt,
                                              u16* __restrict__ ctx) {
  const int s0 = blockIdx.x * 64;
  const int h  = blockIdx.y;
  const int b  = blockIdx.z;
  const int kvh = h >> 1;
  const int tid = threadIdx.x, lane = tid & 63, w = tid >> 6;
  const int l15 = lane & 15, l4 = lane >> 4;
  __shared__ u16 plds[4][16 * 32];
  const u16* qbase = qq + (size_t)(b * 16 + h) * SQ * HD_;
  const u16* kbase = kk + (size_t)(b * 8 + kvh) * SQ * HD_;
  const u16* vbase = vt + (size_t)(b * 8 + kvh) * HD_ * SQ;
  const int sw = s0 + w * 16;

  s8v qf[4];
#pragma unroll
  for (int c = 0; c < 4; c++)
    qf[c] = *(const s8v*)(qbase + (size_t)(sw + l15) * HD_ + c * 32 + l4 * 8);

  f4v o[8] = {};
  float mrow[4] = {-1e30f, -1e30f, -1e30f, -1e30f};
  float lrow[4] = {0.f, 0.f, 0.f, 0.f};
  u16* pl = plds[w];

  for (int t0 = 0; t0 < s0 + 64; t0 += 32) {
    // scores: D[s_local][t_local], A=Q (m=s), B=K^T (n=t)
    f4v sc[2] = {};
#pragma unroll
    for (int tt = 0; tt < 2; tt++) {
#pragma unroll
      for (int c = 0; c < 4; c++) {
        s8v kf = *(const s8v*)(kbase + (size_t)(t0 + tt * 16 + l15) * HD_ + c * 32 + l4 * 8);
        sc[tt] = __builtin_amdgcn_mfma_f32_16x16x32_bf16(qf[c], kf, sc[tt], 0, 0, 0);
      }
    }
    // causal mask (only near/past diagonal for this wave)
    if (t0 + 31 > sw) {
#pragma unroll
      for (int tt = 0; tt < 2; tt++)
#pragma unroll
        for (int r = 0; r < 4; r++) {
          int tg = t0 + tt * 16 + l15;
          int sg = sw + l4 * 4 + r;
          if (tg > sg) sc[tt][r] = -1e30f;
        }
    }
    // online softmax: rows live across the 16 lanes of each quarter-group
    float pm[4];
#pragma unroll
    for (int r = 0; r < 4; r++) pm[r] = fmaxf(sc[0][r], sc[1][r]);
#pragma unroll
    for (int mk = 1; mk < 16; mk <<= 1)
#pragma unroll
      for (int r = 0; r < 4; r++) pm[r] = fmaxf(pm[r], __shfl_xor(pm[r], mk));
    float sf[4], rs[4];
    u16 pv[2][4];
#pragma unroll
    for (int r = 0; r < 4; r++) {
      float mn = fmaxf(mrow[r], pm[r]);
      sf[r] = exp2f((mrow[r] - mn) * 1.44269504f);
      mrow[r] = mn;
      rs[r] = 0.f;
#pragma unroll
      for (int tt = 0; tt < 2; tt++) {
        float p = exp2f((sc[tt][r] - mn) * 1.44269504f);
        rs[r] += p;
        pv[tt][r] = f2b(p);
      }
    }
#pragma unroll
    for (int mk = 1; mk < 16; mk <<= 1)
#pragma unroll
      for (int r = 0; r < 4; r++) rs[r] += __shfl_xor(rs[r], mk);
#pragma unroll
    for (int r = 0; r < 4; r++) lrow[r] = lrow[r] * sf[r] + rs[r];
#pragma unroll
    for (int dd = 0; dd < 8; dd++)
#pragma unroll
      for (int r = 0; r < 4; r++) o[dd][r] *= sf[r];
    // P -> LDS (wave-private), then read back as A-fragment
#pragma unroll
    for (int tt = 0; tt < 2; tt++)
#pragma unroll
      for (int r = 0; r < 4; r++)
        pl[(l4 * 4 + r) * 32 + tt * 16 + l15] = pv[tt][r];
    asm volatile("s_waitcnt lgkmcnt(0)" ::: "memory");
    __builtin_amdgcn_sched_barrier(0);
    s8v pf = *(const s8v*)(pl + l15 * 32 + l4 * 8);
    // PV: B = V (k=t, n=d) from transposed vt[d][t]
#pragma unroll
    for (int dd = 0; dd < 8; dd++) {
      s8v vf = *(const s8v*)(vbase + (size_t)(dd * 16 + l15) * SQ + t0 + l4 * 8);
      o[dd] = __builtin_amdgcn_mfma_f32_16x16x32_bf16(pf, vf, o[dd], 0, 0, 0);
    }
  }
  // epilogue: ctx[b, s, h*HD + d]
  float inv[4];
#pragma unroll
  for (int r = 0; r < 4; r++) inv[r] = 1.f / lrow[r];
#pragma unroll
  for (int dd = 0; dd < 8; dd++)
#pragma unroll
    for (int r = 0; r < 4; r++)
      ctx[((size_t)(b * SQ + sw + l4 * 4 + r)) * HDIM + h * HD_ + dd * 16 + l15] =
          f2b(o[dd][r] * inv[r]);
}

extern "C" void kernel_launch(void* const* d_in, const int* in_sizes, int n_in,
                              void* d_out, int out_size, void* d_ws, size_t ws_size,
                              hipStream_t stream) {
  const float* x     = (const float*)d_in[0];
  const float* wq    = (const float*)d_in[1];
  const float* wk    = (const float*)d_in[2];
  const float* wv    = (const float*)d_in[3];
  const float* wo    = (const float*)d_in[4];
  const float* rms_w = (const float*)d_in[5];
  const int*   pos   = (const int*)d_in[6];
  float* out = (float*)d_out;

  u16* w = (u16*)d_ws;
  u16* xb   = w;                    // 8388608  x bf16 [M=4096,K=2048]; later reused as ctx
  u16* wqt  = xb   + 8388608;       // 4194304  wq^T  [2048,2048]; later reused (qq base)
  u16* wkt  = wqt  + 4194304;       // 2097152  wk^T  [1024,2048]
  u16* wvt  = wkt  + 2097152;       // 2097152  wv^T  [1024,2048]
  u16* wot  = wvt  + 2097152;       // 4194304  wo^T  [2048,2048]
  u16* qraw = wot  + 4194304;       // 8388608
  u16* kraw = qraw + 8388608;       // 4194304
  u16* vraw = kraw + 4194304;       // 4194304
  u16* kkb  = vraw + 4194304;       // 4194304  kk[b,kv,s,d]
  u16* vtb  = kkb  + 4194304;       // 4194304  vt[b,kv,d,s]
  u16* qqb  = wqt;                  // alias: qq[b,h,s,d] (8388608) over wqt+wkt+wvt (dead)
  u16* ctxb = xb;                   // alias: ctx bf16 [4096,2048] over xb (dead)

  k_cast<<<8192, 256, 0, stream>>>(x, xb, 2097152);
  k_transpose_cast<<<dim3(64, 64), dim3(32, 8), 0, stream>>>(wq, wqt, 2048, 2048);
  k_transpose_cast<<<dim3(32, 64), dim3(32, 8), 0, stream>>>(wk, wkt, 2048, 1024);
  k_transpose_cast<<<dim3(32, 64), dim3(32, 8), 0, stream>>>(wv, wvt, 2048, 1024);
  k_transpose_cast<<<dim3(64, 64), dim3(32, 8), 0, stream>>>(wo, wot, 2048, 2048);

  k_gemm<0><<<dim3(16, 32), 256, 0, stream>>>(xb, wqt, qraw, 4096, 2048, 2048);
  k_gemm<0><<<dim3(8, 32), 256, 0, stream>>>(xb, wkt, kraw, 4096, 1024, 2048);
  k_gemm<0><<<dim3(8, 32), 256, 0, stream>>>(xb, wvt, vraw, 4096, 1024, 2048);

  k_normrope<<<4096, 256, 0, stream>>>(qraw, kraw, vraw, rms_w, pos, qqb, kkb, vtb);

  k_attn<<<dim3(32, 16, 2), 256, 0, stream>>>(qqb, kkb, vtb, ctxb);

  k_gemm<1><<<dim3(16, 32), 256, 0, stream>>>(ctxb, wot, d_out, 4096, 2048, 2048);
}

// Round 2
// 496.564 us; speedup vs baseline: 1.3840x; 1.3840x over previous
//
#include <hip/hip_runtime.h>
#include <hip/hip_bf16.h>
#include <stdint.h>

typedef unsigned short u16;
typedef __attribute__((ext_vector_type(8))) short s8v;   // 8 bf16 (4 VGPRs)
typedef __attribute__((ext_vector_type(4))) float f4v;   // 4 fp32

#define SQ   2048
#define HDIM 2048
#define HD_  128
#define NH_  16
#define NKV_ 8

__device__ __forceinline__ u16 f2b(float f) {
  uint32_t u = __builtin_bit_cast(uint32_t, f);
  u += 0x7fffu + ((u >> 16) & 1u);
  return (u16)(u >> 16);
}
__device__ __forceinline__ float b2f(u16 v) {
  uint32_t u = ((uint32_t)v) << 16;
  return __builtin_bit_cast(float, u);
}

// ---------------- cast f32 -> bf16, 4 elems/thread ----------------
__global__ __launch_bounds__(256) void k_cast(const float* __restrict__ in,
                                              u16* __restrict__ out, int n4) {
  int i = blockIdx.x * 256 + threadIdx.x;
  if (i >= n4) return;
  f4v v = *(const f4v*)(in + (size_t)i * 4);
  union { u16 s[4]; uint64_t u; } o;
  o.s[0] = f2b(v[0]); o.s[1] = f2b(v[1]); o.s[2] = f2b(v[2]); o.s[3] = f2b(v[3]);
  *(uint64_t*)(out + (size_t)i * 4) = o.u;
}

// ---------------- transpose + cast: in (rows x cols) f32 -> out (cols x rows) bf16 ----------------
__global__ __launch_bounds__(256) void k_transpose_cast(const float* __restrict__ in,
                                                        u16* __restrict__ out,
                                                        int rows, int cols) {
  __shared__ float tile[32][33];
  int tx = threadIdx.x, ty = threadIdx.y;
  int c0 = blockIdx.x * 32, r0 = blockIdx.y * 32;
#pragma unroll
  for (int i = 0; i < 32; i += 8)
    tile[ty + i][tx] = in[(size_t)(r0 + ty + i) * cols + c0 + tx];
  __syncthreads();
#pragma unroll
  for (int i = 0; i < 32; i += 8)
    out[(size_t)(c0 + ty + i) * rows + r0 + tx] = f2b(tile[tx][ty + i]);
}

// ---------------- bf16 GEMM: C[M,N] = A[M,K] * Bt[N,K]^T ----------------
template <int F32OUT>
__global__ __launch_bounds__(256) void k_gemm(const u16* __restrict__ A,
                                              const u16* __restrict__ Bt,
                                              void* __restrict__ C,
                                              int M, int N, int K) {
  __shared__ u16 As[128 * 64];
  __shared__ u16 Bs[128 * 64];
  const int tid = threadIdx.x;
  const int lane = tid & 63, wvi = tid >> 6;
  const int wm = wvi >> 1, wn = wvi & 1;
  const int l15 = lane & 15, l4 = lane >> 4;
  const int m0 = blockIdx.y * 128, n0 = blockIdx.x * 128;
  f4v acc[4][4] = {};
  for (int k0 = 0; k0 < K; k0 += 64) {
#pragma unroll
    for (int i = 0; i < 4; i++) {
      int ci = i * 256 + tid;
      int r  = ci >> 3;
      int cb = (ci & 7) * 16;
      int sw = cb ^ ((r & 7) << 4);
      *(f4v*)((char*)As + r * 128 + sw) =
          *(const f4v*)((const char*)(A + (size_t)(m0 + r) * K + k0) + cb);
      *(f4v*)((char*)Bs + r * 128 + sw) =
          *(const f4v*)((const char*)(Bt + (size_t)(n0 + r) * K + k0) + cb);
    }
    __syncthreads();
#pragma unroll
    for (int kk = 0; kk < 2; kk++) {
      s8v af[4], bf[4];
#pragma unroll
      for (int i = 0; i < 4; i++) {
        int ra = wm * 64 + i * 16 + l15;
        af[i] = *(const s8v*)((const char*)As + ra * 128 +
                              ((kk * 64 + l4 * 16) ^ ((ra & 7) << 4)));
        int rb = wn * 64 + i * 16 + l15;
        bf[i] = *(const s8v*)((const char*)Bs + rb * 128 +
                              ((kk * 64 + l4 * 16) ^ ((rb & 7) << 4)));
      }
#pragma unroll
      for (int i = 0; i < 4; i++)
#pragma unroll
        for (int j = 0; j < 4; j++)
          acc[i][j] = __builtin_amdgcn_mfma_f32_16x16x32_bf16(af[i], bf[j], acc[i][j], 0, 0, 0);
    }
    __syncthreads();
  }
#pragma unroll
  for (int i = 0; i < 4; i++) {
#pragma unroll
    for (int j = 0; j < 4; j++) {
      int mb = m0 + wm * 64 + i * 16 + l4 * 4;
      int nn = n0 + wn * 64 + j * 16 + l15;
#pragma unroll
      for (int r = 0; r < 4; r++) {
        float v = acc[i][j][r];
        if (F32OUT) ((float*)C)[(size_t)(mb + r) * N + nn] = v;
        else        ((u16*)C)[(size_t)(mb + r) * N + nn]  = f2b(v);
      }
    }
  }
}

// ---------------- RMSNorm + RoPE + layout repack ----------------
__global__ __launch_bounds__(256) void k_normrope(const u16* __restrict__ q_raw,
                                                  const u16* __restrict__ k_raw,
                                                  const u16* __restrict__ v_raw,
                                                  const float* __restrict__ rms_w,
                                                  const int* __restrict__ pos_arr,
                                                  u16* __restrict__ qq,
                                                  u16* __restrict__ kko,
                                                  u16* __restrict__ vto) {
  int idx = blockIdx.x;            // b*SQ + s
  int b = idx >> 11, s = idx & 2047;
  int t = threadIdx.x;
  __shared__ float part[256];
  __shared__ float rstdq[16], rstdk[8];
  __shared__ float lcos[64], lsin[64];
  float pos = (float)pos_arr[s];
  if (t < 64) {
    float ang = pos * exp2f(-0.20762050593046f * (float)t);
    float sn, cs;
    sincosf(ang, &sn, &cs);
    lcos[t] = cs; lsin[t] = sn;
  }
  // ---- Q ----
  const u16* qr = q_raw + (size_t)idx * 2048;
  int h = t & 15, ch = t >> 4;
  float qv[8]; float ss = 0.f;
#pragma unroll
  for (int j = 0; j < 8; j++) {
    float v = b2f(qr[(ch * 8 + j) * 16 + h]);
    qv[j] = v; ss += v * v;
  }
  part[t] = ss;
  __syncthreads();
  if (t < 16) {
    float tot = 0.f;
#pragma unroll
    for (int c = 0; c < 16; c++) tot += part[c * 16 + t];
    rstdq[t] = rsqrtf(tot * (1.f / 128.f) + 1e-6f);
  }
  __syncthreads();
  {
    float rs = rstdq[h];
    s8v ov;
#pragma unroll
    for (int p = 0; p < 4; p++) {
      int d0 = ch * 8 + p * 2;
      float v0 = qv[p * 2]     * rs * rms_w[d0];
      float v1 = qv[p * 2 + 1] * rs * rms_w[d0 + 1];
      float cs = lcos[d0 >> 1], sn = lsin[d0 >> 1];
      ov[p * 2]     = (short)f2b((v0 * cs - v1 * sn) * 0.08838834764831845f);
      ov[p * 2 + 1] = (short)f2b((v0 * sn + v1 * cs) * 0.08838834764831845f);
    }
    *(s8v*)(qq + ((size_t)(b * 16 + h) * SQ + s) * HD_ + ch * 8) = ov;
  }
  __syncthreads();
  // ---- K/V (threads < 128) ----
  const u16* kr = k_raw + (size_t)idx * 1024;
  const u16* vr = v_raw + (size_t)idx * 1024;
  int kv = t & 7, ch2 = t >> 3;
  float kvs[8]; float ssk = 0.f;
  if (t < 128) {
#pragma unroll
    for (int j = 0; j < 8; j++) {
      float v = b2f(kr[(ch2 * 8 + j) * 8 + kv]);
      kvs[j] = v; ssk += v * v;
    }
    part[t] = ssk;
  }
  __syncthreads();
  if (t < 8) {
    float tot = 0.f;
#pragma unroll
    for (int c = 0; c < 16; c++) tot += part[c * 8 + t];
    rstdk[t] = rsqrtf(tot * (1.f / 128.f) + 1e-6f);
  }
  __syncthreads();
  if (t < 128) {
    float rs = rstdk[kv];
    s8v ov;
#pragma unroll
    for (int p = 0; p < 4; p++) {
      int d0 = ch2 * 8 + p * 2;
      float v0 = kvs[p * 2]     * rs * rms_w[d0];
      float v1 = kvs[p * 2 + 1] * rs * rms_w[d0 + 1];
      float cs = lcos[d0 >> 1], sn = lsin[d0 >> 1];
      ov[p * 2]     = (short)f2b(v0 * cs - v1 * sn);
      ov[p * 2 + 1] = (short)f2b(v0 * sn + v1 * cs);
    }
    *(s8v*)(kko + ((size_t)(b * 8 + kv) * SQ + s) * HD_ + ch2 * 8) = ov;
#pragma unroll
    for (int j = 0; j < 8; j++) {
      int d = ch2 * 8 + j;
      vto[((size_t)(b * 8 + kv) * HD_ + d) * SQ + s] = vr[d * 8 + kv];
    }
  }
}

// ---------------- causal flash attention v2 ----------------
// 32 Q rows/wave (2x16 groups), K double-buffered in regs, V issued early,
// per-wave loop bound, causal pairing via (b,tile) remap.
__device__ __forceinline__ void attn_step(const s8v (&qf)[2][4],
                                          const s8v (&kf)[2][4],
                                          s8v (&kn)[2][4],
                                          f4v (&o)[2][8],
                                          float (&mrow)[2][4],
                                          float (&lrow)[2][4],
                                          const u16* kbase, const u16* vbase,
                                          u16* pl0, u16* pl1,
                                          int t0, int sw, int l15, int l4) {
  // V fragments for this tile — issued first, used ~500cyc later
  s8v vf[8];
#pragma unroll
  for (int dd = 0; dd < 8; dd++)
    vf[dd] = *(const s8v*)(vbase + (size_t)(dd * 16 + l15) * SQ + t0 + l4 * 8);
  // prefetch K fragments for next tile (clamped; values unused when OOB)
  int tn = t0 + 32; if (tn >= SQ) tn = 0;
#pragma unroll
  for (int tt = 0; tt < 2; tt++)
#pragma unroll
    for (int c = 0; c < 4; c++)
      kn[tt][c] = *(const s8v*)(kbase + (size_t)(tn + tt * 16 + l15) * HD_ + c * 32 + l4 * 8);
  // QK^T for both row groups
  f4v sc[2][2] = {};
  __builtin_amdgcn_s_setprio(1);
#pragma unroll
  for (int g = 0; g < 2; g++)
#pragma unroll
    for (int tt = 0; tt < 2; tt++)
#pragma unroll
      for (int c = 0; c < 4; c++)
        sc[g][tt] = __builtin_amdgcn_mfma_f32_16x16x32_bf16(qf[g][c], kf[tt][c], sc[g][tt], 0, 0, 0);
  __builtin_amdgcn_s_setprio(0);
  // causal mask (only the diagonal tile reaches here with t0 == sw)
  if (t0 >= sw) {
#pragma unroll
    for (int g = 0; g < 2; g++)
#pragma unroll
      for (int tt = 0; tt < 2; tt++)
#pragma unroll
        for (int r = 0; r < 4; r++) {
          int tg = t0 + tt * 16 + l15;
          int sg = sw + g * 16 + l4 * 4 + r;
          if (tg > sg) sc[g][tt][r] = -1e30f;
        }
  }
  // online softmax per group
#pragma unroll
  for (int g = 0; g < 2; g++) {
    u16* pl = g ? pl1 : pl0;
    float pm[4];
#pragma unroll
    for (int r = 0; r < 4; r++) pm[r] = fmaxf(sc[g][0][r], sc[g][1][r]);
#pragma unroll
    for (int mk = 1; mk < 16; mk <<= 1)
#pragma unroll
      for (int r = 0; r < 4; r++) pm[r] = fmaxf(pm[r], __shfl_xor(pm[r], mk));
    float sf[4], rs[4];
    u16 pv[2][4];
#pragma unroll
    for (int r = 0; r < 4; r++) {
      float mn = fmaxf(mrow[g][r], pm[r]);
      sf[r] = exp2f((mrow[g][r] - mn) * 1.44269504f);
      mrow[g][r] = mn;
      rs[r] = 0.f;
#pragma unroll
      for (int tt = 0; tt < 2; tt++) {
        float p = exp2f((sc[g][tt][r] - mn) * 1.44269504f);
        rs[r] += p;
        pv[tt][r] = f2b(p);
      }
    }
#pragma unroll
    for (int mk = 1; mk < 16; mk <<= 1)
#pragma unroll
      for (int r = 0; r < 4; r++) rs[r] += __shfl_xor(rs[r], mk);
#pragma unroll
    for (int r = 0; r < 4; r++) lrow[g][r] = lrow[g][r] * sf[r] + rs[r];
#pragma unroll
    for (int dd = 0; dd < 8; dd++)
#pragma unroll
      for (int r = 0; r < 4; r++) o[g][dd][r] *= sf[r];
#pragma unroll
    for (int tt = 0; tt < 2; tt++)
#pragma unroll
      for (int r = 0; r < 4; r++)
        pl[(l4 * 4 + r) * 32 + tt * 16 + l15] = pv[tt][r];
  }
  asm volatile("s_waitcnt lgkmcnt(0)" ::: "memory");
  __builtin_amdgcn_sched_barrier(0);
  s8v pf0 = *(const s8v*)(pl0 + l15 * 32 + l4 * 8);
  s8v pf1 = *(const s8v*)(pl1 + l15 * 32 + l4 * 8);
  __builtin_amdgcn_s_setprio(1);
#pragma unroll
  for (int dd = 0; dd < 8; dd++) {
    o[0][dd] = __builtin_amdgcn_mfma_f32_16x16x32_bf16(pf0, vf[dd], o[0][dd], 0, 0, 0);
    o[1][dd] = __builtin_amdgcn_mfma_f32_16x16x32_bf16(pf1, vf[dd], o[1][dd], 0, 0, 0);
  }
  __builtin_amdgcn_s_setprio(0);
}

__global__ __launch_bounds__(256, 2) void k_attn(const u16* __restrict__ qq,
                                                 const u16* __restrict__ kk,
                                                 const u16* __restrict__ vt,
                                                 u16* __restrict__ ctx) {
  // causal load-balance pairing: b=1 blocks take mirrored tiles
  const int tile = (blockIdx.z == 1) ? (15 - (int)blockIdx.x) : (int)blockIdx.x;
  const int s0 = tile * 128;
  const int h  = blockIdx.y;
  const int b  = blockIdx.z;
  const int kvh = h >> 1;
  const int tid = threadIdx.x, lane = tid & 63, w = tid >> 6;
  const int l15 = lane & 15, l4 = lane >> 4;
  __shared__ u16 plds[4][2][16 * 32];
  const u16* qbase = qq + (size_t)(b * 16 + h) * SQ * HD_;
  const u16* kbase = kk + (size_t)(b * 8 + kvh) * SQ * HD_;
  const u16* vbase = vt + (size_t)(b * 8 + kvh) * HD_ * SQ;
  const int sw = s0 + w * 32;
  u16* pl0 = plds[w][0];
  u16* pl1 = plds[w][1];

  s8v qf[2][4];
#pragma unroll
  for (int g = 0; g < 2; g++)
#pragma unroll
    for (int c = 0; c < 4; c++)
      qf[g][c] = *(const s8v*)(qbase + (size_t)(sw + g * 16 + l15) * HD_ + c * 32 + l4 * 8);

  f4v o[2][8] = {};
  float mrow[2][4], lrow[2][4];
#pragma unroll
  for (int g = 0; g < 2; g++)
#pragma unroll
    for (int r = 0; r < 4; r++) { mrow[g][r] = -1e30f; lrow[g][r] = 0.f; }

  s8v kfa[2][4], kfb[2][4];
#pragma unroll
  for (int tt = 0; tt < 2; tt++)
#pragma unroll
    for (int c = 0; c < 4; c++)
      kfa[tt][c] = *(const s8v*)(kbase + (size_t)(tt * 16 + l15) * HD_ + c * 32 + l4 * 8);

  const int bound = sw + 32;
  int t0 = 0;
  while (1) {
    attn_step(qf, kfa, kfb, o, mrow, lrow, kbase, vbase, pl0, pl1, t0, sw, l15, l4);
    t0 += 32; if (t0 >= bound) break;
    attn_step(qf, kfb, kfa, o, mrow, lrow, kbase, vbase, pl0, pl1, t0, sw, l15, l4);
    t0 += 32; if (t0 >= bound) break;
  }

  float inv[2][4];
#pragma unroll
  for (int g = 0; g < 2; g++)
#pragma unroll
    for (int r = 0; r < 4; r++) inv[g][r] = 1.f / lrow[g][r];
#pragma unroll
  for (int g = 0; g < 2; g++)
#pragma unroll
    for (int dd = 0; dd < 8; dd++)
#pragma unroll
      for (int r = 0; r < 4; r++)
        ctx[((size_t)(b * SQ + sw + g * 16 + l4 * 4 + r)) * HDIM + h * HD_ + dd * 16 + l15] =
            f2b(o[g][dd][r] * inv[g][r]);
}

extern "C" void kernel_launch(void* const* d_in, const int* in_sizes, int n_in,
                              void* d_out, int out_size, void* d_ws, size_t ws_size,
                              hipStream_t stream) {
  const float* x     = (const float*)d_in[0];
  const float* wq    = (const float*)d_in[1];
  const float* wk    = (const float*)d_in[2];
  const float* wv    = (const float*)d_in[3];
  const float* wo    = (const float*)d_in[4];
  const float* rms_w = (const float*)d_in[5];
  const int*   pos   = (const int*)d_in[6];

  u16* w = (u16*)d_ws;
  u16* xb   = w;                    // 8388608  x bf16 [4096,2048]; later reused as ctx
  u16* wqt  = xb   + 8388608;       // 4194304  wq^T; later reused as qq
  u16* wkt  = wqt  + 4194304;       // 2097152
  u16* wvt  = wkt  + 2097152;       // 2097152
  u16* wot  = wvt  + 2097152;       // 4194304
  u16* qraw = wot  + 4194304;       // 8388608
  u16* kraw = qraw + 8388608;       // 4194304
  u16* vraw = kraw + 4194304;       // 4194304
  u16* kkb  = vraw + 4194304;       // 4194304  kk[b,kv,s,d]
  u16* vtb  = kkb  + 4194304;       // 4194304  vt[b,kv,d,s]
  u16* qqb  = wqt;                  // alias over wqt..wvt (dead after QKV gemms)
  u16* ctxb = xb;                   // alias over xb (dead after gemms)

  k_cast<<<8192, 256, 0, stream>>>(x, xb, 2097152);
  k_transpose_cast<<<dim3(64, 64), dim3(32, 8), 0, stream>>>(wq, wqt, 2048, 2048);
  k_transpose_cast<<<dim3(32, 64), dim3(32, 8), 0, stream>>>(wk, wkt, 2048, 1024);
  k_transpose_cast<<<dim3(32, 64), dim3(32, 8), 0, stream>>>(wv, wvt, 2048, 1024);
  k_transpose_cast<<<dim3(64, 64), dim3(32, 8), 0, stream>>>(wo, wot, 2048, 2048);

  k_gemm<0><<<dim3(16, 32), 256, 0, stream>>>(xb, wqt, qraw, 4096, 2048, 2048);
  k_gemm<0><<<dim3(8, 32), 256, 0, stream>>>(xb, wkt, kraw, 4096, 1024, 2048);
  k_gemm<0><<<dim3(8, 32), 256, 0, stream>>>(xb, wvt, vraw, 4096, 1024, 2048);

  k_normrope<<<4096, 256, 0, stream>>>(qraw, kraw, vraw, rms_w, pos, qqb, kkb, vtb);

  k_attn<<<dim3(16, 16, 2), 256, 0, stream>>>(qqb, kkb, vtb, ctxb);

  k_gemm<1><<<dim3(16, 32), 256, 0, stream>>>(ctxb, wot, d_out, 4096, 2048, 2048);
}

// Round 3
// 355.552 us; speedup vs baseline: 1.9329x; 1.3966x over previous
//
#include <hip/hip_runtime.h>
#include <hip/hip_bf16.h>
#include <stdint.h>

typedef unsigned short u16;
typedef __attribute__((ext_vector_type(8))) short s8v;   // 8 bf16 (4 VGPRs)
typedef __attribute__((ext_vector_type(4))) float f4v;   // 4 fp32

#define SQ   2048
#define HDIM 2048
#define HD_  128
#define NH_  16
#define NKV_ 8

__device__ __forceinline__ u16 f2b(float f) {
  uint32_t u = __builtin_bit_cast(uint32_t, f);
  u += 0x7fffu + ((u >> 16) & 1u);
  return (u16)(u >> 16);
}
__device__ __forceinline__ float b2f(u16 v) {
  uint32_t u = ((uint32_t)v) << 16;
  return __builtin_bit_cast(float, u);
}

// ---------------- cast f32 -> bf16, 4 elems/thread ----------------
__global__ __launch_bounds__(256) void k_cast(const float* __restrict__ in,
                                              u16* __restrict__ out, int n4) {
  int i = blockIdx.x * 256 + threadIdx.x;
  if (i >= n4) return;
  f4v v = *(const f4v*)(in + (size_t)i * 4);
  union { u16 s[4]; uint64_t u; } o;
  o.s[0] = f2b(v[0]); o.s[1] = f2b(v[1]); o.s[2] = f2b(v[2]); o.s[3] = f2b(v[3]);
  *(uint64_t*)(out + (size_t)i * 4) = o.u;
}

// ---------------- transpose + cast ----------------
__global__ __launch_bounds__(256) void k_transpose_cast(const float* __restrict__ in,
                                                        u16* __restrict__ out,
                                                        int rows, int cols) {
  __shared__ float tile[32][33];
  int tx = threadIdx.x, ty = threadIdx.y;
  int c0 = blockIdx.x * 32, r0 = blockIdx.y * 32;
#pragma unroll
  for (int i = 0; i < 32; i += 8)
    tile[ty + i][tx] = in[(size_t)(r0 + ty + i) * cols + c0 + tx];
  __syncthreads();
#pragma unroll
  for (int i = 0; i < 32; i += 8)
    out[(size_t)(c0 + ty + i) * rows + r0 + tx] = f2b(tile[tx][ty + i]);
}

// ---------------- bf16 GEMM: C[M,N] = A[M,K] * Bt[N,K]^T ----------------
// 128x128 tile, BK=64, 4 waves (2x2). global_load_lds staging:
// linear LDS dest, inverse-swizzled global source, swizzled reads (rule 21).
template <int F32OUT>
__global__ __launch_bounds__(256) void k_gemm(const u16* __restrict__ A,
                                              const u16* __restrict__ Bt,
                                              void* __restrict__ C,
                                              int M, int N, int K) {
  __shared__ __align__(16) u16 As[128 * 64];
  __shared__ __align__(16) u16 Bs[128 * 64];
  const int tid = threadIdx.x;
  const int lane = tid & 63, wvi = tid >> 6;
  const int wm = wvi >> 1, wn = wvi & 1;
  const int l15 = lane & 15, l4 = lane >> 4;
  const int m0 = blockIdx.y * 128, n0 = blockIdx.x * 128;
  auto* As3 = (__attribute__((address_space(3))) char*)As;
  auto* Bs3 = (__attribute__((address_space(3))) char*)Bs;
  // per-lane source mapping for the 4 staging calls (r, inverse-swizzled chunk)
  int srow[4], soff[4];
#pragma unroll
  for (int i = 0; i < 4; i++) {
    int slot = wvi * 4096 + i * 1024 + lane * 16;
    int r = slot >> 7;                     // 128 B per tile row
    int gc = ((slot >> 4) & 7) ^ (r & 7);  // inverse swizzle (XOR is involution)
    srow[i] = r; soff[i] = gc * 16;
  }
  f4v acc[4][4] = {};
  for (int k0 = 0; k0 < K; k0 += 64) {
#pragma unroll
    for (int i = 0; i < 4; i++) {
      const char* gA = (const char*)(A + (size_t)(m0 + srow[i]) * K + k0) + soff[i];
      const char* gB = (const char*)(Bt + (size_t)(n0 + srow[i]) * K + k0) + soff[i];
      __builtin_amdgcn_global_load_lds((__attribute__((address_space(1))) void*)gA,
                                       (__attribute__((address_space(3))) void*)(As3 + wvi * 4096 + i * 1024),
                                       16, 0, 0);
      __builtin_amdgcn_global_load_lds((__attribute__((address_space(1))) void*)gB,
                                       (__attribute__((address_space(3))) void*)(Bs3 + wvi * 4096 + i * 1024),
                                       16, 0, 0);
    }
    __syncthreads();   // drains vmcnt(0) -> tiles resident
#pragma unroll
    for (int kk = 0; kk < 2; kk++) {
      s8v af[4], bf[4];
#pragma unroll
      for (int i = 0; i < 4; i++) {
        int ra = wm * 64 + i * 16 + l15;
        af[i] = *(const s8v*)((const char*)As + ra * 128 +
                              ((kk * 64 + l4 * 16) ^ ((ra & 7) << 4)));
        int rb = wn * 64 + i * 16 + l15;
        bf[i] = *(const s8v*)((const char*)Bs + rb * 128 +
                              ((kk * 64 + l4 * 16) ^ ((rb & 7) << 4)));
      }
#pragma unroll
      for (int i = 0; i < 4; i++)
#pragma unroll
        for (int j = 0; j < 4; j++)
          acc[i][j] = __builtin_amdgcn_mfma_f32_16x16x32_bf16(af[i], bf[j], acc[i][j], 0, 0, 0);
    }
    __syncthreads();
  }
#pragma unroll
  for (int i = 0; i < 4; i++) {
#pragma unroll
    for (int j = 0; j < 4; j++) {
      int mb = m0 + wm * 64 + i * 16 + l4 * 4;
      int nn = n0 + wn * 64 + j * 16 + l15;
#pragma unroll
      for (int r = 0; r < 4; r++) {
        float v = acc[i][j][r];
        if (F32OUT) ((float*)C)[(size_t)(mb + r) * N + nn] = v;
        else        ((u16*)C)[(size_t)(mb + r) * N + nn]  = f2b(v);
      }
    }
  }
}

// ---------------- RMSNorm + RoPE + layout repack ----------------
__global__ __launch_bounds__(256) void k_normrope(const u16* __restrict__ q_raw,
                                                  const u16* __restrict__ k_raw,
                                                  const u16* __restrict__ v_raw,
                                                  const float* __restrict__ rms_w,
                                                  const int* __restrict__ pos_arr,
                                                  u16* __restrict__ qq,
                                                  u16* __restrict__ kko,
                                                  u16* __restrict__ vto) {
  int idx = blockIdx.x;            // b*SQ + s
  int b = idx >> 11, s = idx & 2047;
  int t = threadIdx.x;
  __shared__ float part[256];
  __shared__ float rstdq[16], rstdk[8];
  __shared__ float lcos[64], lsin[64];
  float pos = (float)pos_arr[s];
  if (t < 64) {
    float ang = pos * exp2f(-0.20762050593046f * (float)t);
    float sn, cs;
    sincosf(ang, &sn, &cs);
    lcos[t] = cs; lsin[t] = sn;
  }
  // ---- Q ----
  const u16* qr = q_raw + (size_t)idx * 2048;
  int h = t & 15, ch = t >> 4;
  float qv[8]; float ss = 0.f;
#pragma unroll
  for (int j = 0; j < 8; j++) {
    float v = b2f(qr[(ch * 8 + j) * 16 + h]);
    qv[j] = v; ss += v * v;
  }
  part[t] = ss;
  __syncthreads();
  if (t < 16) {
    float tot = 0.f;
#pragma unroll
    for (int c = 0; c < 16; c++) tot += part[c * 16 + t];
    rstdq[t] = rsqrtf(tot * (1.f / 128.f) + 1e-6f);
  }
  __syncthreads();
  {
    float rs = rstdq[h];
    s8v ov;
#pragma unroll
    for (int p = 0; p < 4; p++) {
      int d0 = ch * 8 + p * 2;
      float v0 = qv[p * 2]     * rs * rms_w[d0];
      float v1 = qv[p * 2 + 1] * rs * rms_w[d0 + 1];
      float cs = lcos[d0 >> 1], sn = lsin[d0 >> 1];
      ov[p * 2]     = (short)f2b((v0 * cs - v1 * sn) * 0.08838834764831845f);
      ov[p * 2 + 1] = (short)f2b((v0 * sn + v1 * cs) * 0.08838834764831845f);
    }
    *(s8v*)(qq + ((size_t)(b * 16 + h) * SQ + s) * HD_ + ch * 8) = ov;
  }
  __syncthreads();
  // ---- K/V (threads < 128) ----
  const u16* kr = k_raw + (size_t)idx * 1024;
  const u16* vr = v_raw + (size_t)idx * 1024;
  int kv = t & 7, ch2 = t >> 3;
  float kvs[8]; float ssk = 0.f;
  if (t < 128) {
#pragma unroll
    for (int j = 0; j < 8; j++) {
      float v = b2f(kr[(ch2 * 8 + j) * 8 + kv]);
      kvs[j] = v; ssk += v * v;
    }
    part[t] = ssk;
  }
  __syncthreads();
  if (t < 8) {
    float tot = 0.f;
#pragma unroll
    for (int c = 0; c < 16; c++) tot += part[c * 8 + t];
    rstdk[t] = rsqrtf(tot * (1.f / 128.f) + 1e-6f);
  }
  __syncthreads();
  if (t < 128) {
    float rs = rstdk[kv];
    s8v ov;
#pragma unroll
    for (int p = 0; p < 4; p++) {
      int d0 = ch2 * 8 + p * 2;
      float v0 = kvs[p * 2]     * rs * rms_w[d0];
      float v1 = kvs[p * 2 + 1] * rs * rms_w[d0 + 1];
      float cs = lcos[d0 >> 1], sn = lsin[d0 >> 1];
      ov[p * 2]     = (short)f2b(v0 * cs - v1 * sn);
      ov[p * 2 + 1] = (short)f2b(v0 * sn + v1 * cs);
    }
    *(s8v*)(kko + ((size_t)(b * 8 + kv) * SQ + s) * HD_ + ch2 * 8) = ov;
#pragma unroll
    for (int j = 0; j < 8; j++) {
      int d = ch2 * 8 + j;
      vto[((size_t)(b * 8 + kv) * HD_ + d) * SQ + s] = vr[d * 8 + kv];
    }
  }
}

// ---------------- causal flash attention v3 ----------------
// 32 Q rows/wave. Single K/V register buffers with post-consumption reload:
// kf reloaded right after QK^T (hidden under softmax+PV), vf reloaded right
// after PV (hidden under next iter's QK+softmax). T13 defer-max rescale.
__global__ __launch_bounds__(256, 2) void k_attn(const u16* __restrict__ qq,
                                                 const u16* __restrict__ kk,
                                                 const u16* __restrict__ vt,
                                                 u16* __restrict__ ctx) {
  const int tile = (blockIdx.z == 1) ? (15 - (int)blockIdx.x) : (int)blockIdx.x;
  const int s0 = tile * 128;
  const int h  = blockIdx.y;
  const int b  = blockIdx.z;
  const int kvh = h >> 1;
  const int tid = threadIdx.x, lane = tid & 63, w = tid >> 6;
  const int l15 = lane & 15, l4 = lane >> 4;
  __shared__ u16 plds[4][2][16 * 32];
  const u16* qbase = qq + (size_t)(b * 16 + h) * SQ * HD_;
  const u16* kbase = kk + (size_t)(b * 8 + kvh) * SQ * HD_;
  const u16* vbase = vt + (size_t)(b * 8 + kvh) * HD_ * SQ;
  const int sw = s0 + w * 32;
  u16* pl0 = plds[w][0];
  u16* pl1 = plds[w][1];

  s8v qf[2][4];
#pragma unroll
  for (int g = 0; g < 2; g++)
#pragma unroll
    for (int c = 0; c < 4; c++)
      qf[g][c] = *(const s8v*)(qbase + (size_t)(sw + g * 16 + l15) * HD_ + c * 32 + l4 * 8);

  f4v o[2][8] = {};
  float mrow[2][4], lrow[2][4];
#pragma unroll
  for (int g = 0; g < 2; g++)
#pragma unroll
    for (int r = 0; r < 4; r++) { mrow[g][r] = -1e30f; lrow[g][r] = 0.f; }

  s8v kf[2][4], vf[8];
#pragma unroll
  for (int tt = 0; tt < 2; tt++)
#pragma unroll
    for (int c = 0; c < 4; c++)
      kf[tt][c] = *(const s8v*)(kbase + (size_t)(tt * 16 + l15) * HD_ + c * 32 + l4 * 8);
#pragma unroll
  for (int dd = 0; dd < 8; dd++)
    vf[dd] = *(const s8v*)(vbase + (size_t)(dd * 16 + l15) * SQ + l4 * 8);

  const int bound = sw + 32;
  for (int t0 = 0; t0 < bound; t0 += 32) {
    // QK^T (consumes kf)
    f4v sc[2][2] = {};
    __builtin_amdgcn_s_setprio(1);
#pragma unroll
    for (int g = 0; g < 2; g++)
#pragma unroll
      for (int tt = 0; tt < 2; tt++)
#pragma unroll
        for (int c = 0; c < 4; c++)
          sc[g][tt] = __builtin_amdgcn_mfma_f32_16x16x32_bf16(qf[g][c], kf[tt][c], sc[g][tt], 0, 0, 0);
    __builtin_amdgcn_s_setprio(0);
    // reload kf for next tile (latency hides under softmax + PV)
    const int tn = (t0 + 32 < bound) ? (t0 + 32) : 0;
#pragma unroll
    for (int tt = 0; tt < 2; tt++)
#pragma unroll
      for (int c = 0; c < 4; c++)
        kf[tt][c] = *(const s8v*)(kbase + (size_t)(tn + tt * 16 + l15) * HD_ + c * 32 + l4 * 8);
    // causal mask — only the diagonal (last) iteration
    if (t0 >= sw) {
#pragma unroll
      for (int g = 0; g < 2; g++)
#pragma unroll
        for (int tt = 0; tt < 2; tt++)
#pragma unroll
          for (int r = 0; r < 4; r++) {
            int tg = t0 + tt * 16 + l15;
            int sg = sw + g * 16 + l4 * 4 + r;
            if (tg > sg) sc[g][tt][r] = -1e30f;
          }
    }
    // online softmax per row group, T13 defer-max
#pragma unroll
    for (int g = 0; g < 2; g++) {
      u16* pl = g ? pl1 : pl0;
      float pm[4];
#pragma unroll
      for (int r = 0; r < 4; r++) pm[r] = fmaxf(sc[g][0][r], sc[g][1][r]);
#pragma unroll
      for (int mk = 1; mk < 16; mk <<= 1)
#pragma unroll
        for (int r = 0; r < 4; r++) pm[r] = fmaxf(pm[r], __shfl_xor(pm[r], mk));
      int need = 0;
#pragma unroll
      for (int r = 0; r < 4; r++) need |= (pm[r] > mrow[g][r] + 8.f) ? 1 : 0;
      if (__any(need)) {
        float sf[4];
#pragma unroll
        for (int r = 0; r < 4; r++) {
          float mn = fmaxf(mrow[g][r], pm[r]);
          sf[r] = exp2f((mrow[g][r] - mn) * 1.44269504f);
          mrow[g][r] = mn;
          lrow[g][r] *= sf[r];
        }
#pragma unroll
        for (int dd = 0; dd < 8; dd++)
#pragma unroll
          for (int r = 0; r < 4; r++) o[g][dd][r] *= sf[r];
      }
      float rs[4]; u16 pv[2][4];
#pragma unroll
      for (int r = 0; r < 4; r++) {
        rs[r] = 0.f;
#pragma unroll
        for (int tt = 0; tt < 2; tt++) {
          float p = exp2f((sc[g][tt][r] - mrow[g][r]) * 1.44269504f);
          rs[r] += p;
          pv[tt][r] = f2b(p);
        }
      }
#pragma unroll
      for (int mk = 1; mk < 16; mk <<= 1)
#pragma unroll
        for (int r = 0; r < 4; r++) rs[r] += __shfl_xor(rs[r], mk);
#pragma unroll
      for (int r = 0; r < 4; r++) lrow[g][r] += rs[r];
#pragma unroll
      for (int tt = 0; tt < 2; tt++)
#pragma unroll
        for (int r = 0; r < 4; r++)
          pl[(l4 * 4 + r) * 32 + tt * 16 + l15] = pv[tt][r];
    }
    asm volatile("s_waitcnt lgkmcnt(0)" ::: "memory");
    __builtin_amdgcn_sched_barrier(0);
    s8v pf0 = *(const s8v*)(pl0 + l15 * 32 + l4 * 8);
    s8v pf1 = *(const s8v*)(pl1 + l15 * 32 + l4 * 8);
    // PV (consumes vf)
    __builtin_amdgcn_s_setprio(1);
#pragma unroll
    for (int dd = 0; dd < 8; dd++) {
      o[0][dd] = __builtin_amdgcn_mfma_f32_16x16x32_bf16(pf0, vf[dd], o[0][dd], 0, 0, 0);
      o[1][dd] = __builtin_amdgcn_mfma_f32_16x16x32_bf16(pf1, vf[dd], o[1][dd], 0, 0, 0);
    }
    __builtin_amdgcn_s_setprio(0);
    // reload vf for next tile (latency hides under next QK + softmax)
#pragma unroll
    for (int dd = 0; dd < 8; dd++)
      vf[dd] = *(const s8v*)(vbase + (size_t)(dd * 16 + l15) * SQ + tn + l4 * 8);
  }
  // epilogue
  float inv[2][4];
#pragma unroll
  for (int g = 0; g < 2; g++)
#pragma unroll
    for (int r = 0; r < 4; r++) inv[g][r] = 1.f / lrow[g][r];
#pragma unroll
  for (int g = 0; g < 2; g++)
#pragma unroll
    for (int dd = 0; dd < 8; dd++)
#pragma unroll
      for (int r = 0; r < 4; r++)
        ctx[((size_t)(b * SQ + sw + g * 16 + l4 * 4 + r)) * HDIM + h * HD_ + dd * 16 + l15] =
            f2b(o[g][dd][r] * inv[g][r]);
}

extern "C" void kernel_launch(void* const* d_in, const int* in_sizes, int n_in,
                              void* d_out, int out_size, void* d_ws, size_t ws_size,
                              hipStream_t stream) {
  const float* x     = (const float*)d_in[0];
  const float* wq    = (const float*)d_in[1];
  const float* wk    = (const float*)d_in[2];
  const float* wv    = (const float*)d_in[3];
  const float* wo    = (const float*)d_in[4];
  const float* rms_w = (const float*)d_in[5];
  const int*   pos   = (const int*)d_in[6];

  u16* w = (u16*)d_ws;
  u16* xb   = w;                    // 8388608  x bf16 [4096,2048]; later reused as ctx
  u16* wqt  = xb   + 8388608;       // 4194304  wq^T; later reused as qq
  u16* wkt  = wqt  + 4194304;       // 2097152
  u16* wvt  = wkt  + 2097152;       // 2097152
  u16* wot  = wvt  + 2097152;       // 4194304
  u16* qraw = wot  + 4194304;       // 8388608
  u16* kraw = qraw + 8388608;       // 4194304
  u16* vraw = kraw + 4194304;       // 4194304
  u16* kkb  = vraw + 4194304;       // 4194304  kk[b,kv,s,d]
  u16* vtb  = kkb  + 4194304;       // 4194304  vt[b,kv,d,s]
  u16* qqb  = wqt;                  // alias over wqt..wvt (dead after QKV gemms)
  u16* ctxb = xb;                   // alias over xb (dead after gemms)

  k_cast<<<8192, 256, 0, stream>>>(x, xb, 2097152);
  k_transpose_cast<<<dim3(64, 64), dim3(32, 8), 0, stream>>>(wq, wqt, 2048, 2048);
  k_transpose_cast<<<dim3(32, 64), dim3(32, 8), 0, stream>>>(wk, wkt, 2048, 1024);
  k_transpose_cast<<<dim3(32, 64), dim3(32, 8), 0, stream>>>(wv, wvt, 2048, 1024);
  k_transpose_cast<<<dim3(64, 64), dim3(32, 8), 0, stream>>>(wo, wot, 2048, 2048);

  k_gemm<0><<<dim3(16, 32), 256, 0, stream>>>(xb, wqt, qraw, 4096, 2048, 2048);
  k_gemm<0><<<dim3(8, 32), 256, 0, stream>>>(xb, wkt, kraw, 4096, 1024, 2048);
  k_gemm<0><<<dim3(8, 32), 256, 0, stream>>>(xb, wvt, vraw, 4096, 1024, 2048);

  k_normrope<<<4096, 256, 0, stream>>>(qraw, kraw, vraw, rms_w, pos, qqb, kkb, vtb);

  k_attn<<<dim3(16, 16, 2), 256, 0, stream>>>(qqb, kkb, vtb, ctxb);

  k_gemm<1><<<dim3(16, 32), 256, 0, stream>>>(ctxb, wot, d_out, 4096, 2048, 2048);
}

// Round 4
// 320.832 us; speedup vs baseline: 2.1421x; 1.1082x over previous
//
#include <hip/hip_runtime.h>
#include <hip/hip_bf16.h>
#include <stdint.h>

typedef unsigned short u16;
typedef uint32_t u32;
typedef __attribute__((ext_vector_type(8))) short s8v;   // 8 bf16 (4 VGPRs)
typedef __attribute__((ext_vector_type(4))) float f4v;   // 4 fp32
typedef __attribute__((ext_vector_type(4))) unsigned int u4v;

#define SQ   2048
#define HDIM 2048
#define HD_  128
#define NH_  16
#define NKV_ 8

__device__ __forceinline__ u16 f2b(float f) {
  uint32_t u = __builtin_bit_cast(uint32_t, f);
  u += 0x7fffu + ((u >> 16) & 1u);
  return (u16)(u >> 16);
}
__device__ __forceinline__ float b2f(u16 v) {
  uint32_t u = ((uint32_t)v) << 16;
  return __builtin_bit_cast(float, u);
}
__device__ __forceinline__ u32 pk2(float lo, float hi) {
  return (u32)f2b(lo) | ((u32)f2b(hi) << 16);
}

// ---------------- cast f32 -> bf16, 4 elems/thread ----------------
__global__ __launch_bounds__(256) void k_cast(const float* __restrict__ in,
                                              u16* __restrict__ out, int n4) {
  int i = blockIdx.x * 256 + threadIdx.x;
  if (i >= n4) return;
  f4v v = *(const f4v*)(in + (size_t)i * 4);
  union { u16 s[4]; uint64_t u; } o;
  o.s[0] = f2b(v[0]); o.s[1] = f2b(v[1]); o.s[2] = f2b(v[2]); o.s[3] = f2b(v[3]);
  *(uint64_t*)(out + (size_t)i * 4) = o.u;
}

// ---------------- transpose + cast ----------------
__global__ __launch_bounds__(256) void k_transpose_cast(const float* __restrict__ in,
                                                        u16* __restrict__ out,
                                                        int rows, int cols) {
  __shared__ float tile[32][33];
  int tx = threadIdx.x, ty = threadIdx.y;
  int c0 = blockIdx.x * 32, r0 = blockIdx.y * 32;
#pragma unroll
  for (int i = 0; i < 32; i += 8)
    tile[ty + i][tx] = in[(size_t)(r0 + ty + i) * cols + c0 + tx];
  __syncthreads();
#pragma unroll
  for (int i = 0; i < 32; i += 8)
    out[(size_t)(c0 + ty + i) * rows + r0 + tx] = f2b(tile[tx][ty + i]);
}

// ---------------- bf16 GEMM: C[M,N] = A[M,K] * Bt[N,K]^T ----------------
// 128x128 tile, BK=64, 4 waves. global_load_lds staging, rule-21 swizzle.
template <int F32OUT>
__global__ __launch_bounds__(256) void k_gemm(const u16* __restrict__ A,
                                              const u16* __restrict__ Bt,
                                              void* __restrict__ C,
                                              int M, int N, int K) {
  __shared__ __align__(16) u16 As[128 * 64];
  __shared__ __align__(16) u16 Bs[128 * 64];
  const int tid = threadIdx.x;
  const int lane = tid & 63, wvi = tid >> 6;
  const int wm = wvi >> 1, wn = wvi & 1;
  const int l15 = lane & 15, l4 = lane >> 4;
  const int m0 = blockIdx.y * 128, n0 = blockIdx.x * 128;
  auto* As3 = (__attribute__((address_space(3))) char*)As;
  auto* Bs3 = (__attribute__((address_space(3))) char*)Bs;
  int srow[4], soff[4];
#pragma unroll
  for (int i = 0; i < 4; i++) {
    int slot = wvi * 4096 + i * 1024 + lane * 16;
    int r = slot >> 7;
    int gc = ((slot >> 4) & 7) ^ (r & 7);
    srow[i] = r; soff[i] = gc * 16;
  }
  f4v acc[4][4] = {};
  for (int k0 = 0; k0 < K; k0 += 64) {
#pragma unroll
    for (int i = 0; i < 4; i++) {
      const char* gA = (const char*)(A + (size_t)(m0 + srow[i]) * K + k0) + soff[i];
      const char* gB = (const char*)(Bt + (size_t)(n0 + srow[i]) * K + k0) + soff[i];
      __builtin_amdgcn_global_load_lds((__attribute__((address_space(1))) void*)gA,
                                       (__attribute__((address_space(3))) void*)(As3 + wvi * 4096 + i * 1024),
                                       16, 0, 0);
      __builtin_amdgcn_global_load_lds((__attribute__((address_space(1))) void*)gB,
                                       (__attribute__((address_space(3))) void*)(Bs3 + wvi * 4096 + i * 1024),
                                       16, 0, 0);
    }
    __syncthreads();
#pragma unroll
    for (int kk = 0; kk < 2; kk++) {
      s8v af[4], bf[4];
#pragma unroll
      for (int i = 0; i < 4; i++) {
        int ra = wm * 64 + i * 16 + l15;
        af[i] = *(const s8v*)((const char*)As + ra * 128 +
                              ((kk * 64 + l4 * 16) ^ ((ra & 7) << 4)));
        int rb = wn * 64 + i * 16 + l15;
        bf[i] = *(const s8v*)((const char*)Bs + rb * 128 +
                              ((kk * 64 + l4 * 16) ^ ((rb & 7) << 4)));
      }
#pragma unroll
      for (int i = 0; i < 4; i++)
#pragma unroll
        for (int j = 0; j < 4; j++)
          acc[i][j] = __builtin_amdgcn_mfma_f32_16x16x32_bf16(af[i], bf[j], acc[i][j], 0, 0, 0);
    }
    __syncthreads();
  }
#pragma unroll
  for (int i = 0; i < 4; i++) {
#pragma unroll
    for (int j = 0; j < 4; j++) {
      int mb = m0 + wm * 64 + i * 16 + l4 * 4;
      int nn = n0 + wn * 64 + j * 16 + l15;
#pragma unroll
      for (int r = 0; r < 4; r++) {
        float v = acc[i][j][r];
        if (F32OUT) ((float*)C)[(size_t)(mb + r) * N + nn] = v;
        else        ((u16*)C)[(size_t)(mb + r) * N + nn]  = f2b(v);
      }
    }
  }
}

// ---------------- RMSNorm + RoPE + layout repack (fused-QKV input) ----------------
// qkv row (4096 wide): cols 0..2047 = q (col=d*16+h), 2048..3071 = k (d*8+kv),
// 3072..4095 = v. Outputs: qq[b,h,s,d] (q scaled 1/sqrt(HD)), kk[b,kv,s,d], vt[b,kv,d,s]
__global__ __launch_bounds__(256) void k_normrope(const u16* __restrict__ qkv,
                                                  const float* __restrict__ rms_w,
                                                  const int* __restrict__ pos_arr,
                                                  u16* __restrict__ qq,
                                                  u16* __restrict__ kko,
                                                  u16* __restrict__ vto) {
  int idx = blockIdx.x;            // b*SQ + s
  int b = idx >> 11, s = idx & 2047;
  int t = threadIdx.x;
  __shared__ float part[256];
  __shared__ float rstdq[16], rstdk[8];
  __shared__ float lcos[64], lsin[64];
  float pos = (float)pos_arr[s];
  if (t < 64) {
    float ang = pos * exp2f(-0.20762050593046f * (float)t);
    float sn, cs;
    sincosf(ang, &sn, &cs);
    lcos[t] = cs; lsin[t] = sn;
  }
  const u16* qr = qkv + (size_t)idx * 4096;
  const u16* kr = qr + 2048;
  const u16* vr = qr + 3072;
  // ---- Q ----
  int h = t & 15, ch = t >> 4;
  float qv[8]; float ss = 0.f;
#pragma unroll
  for (int j = 0; j < 8; j++) {
    float v = b2f(qr[(ch * 8 + j) * 16 + h]);
    qv[j] = v; ss += v * v;
  }
  part[t] = ss;
  __syncthreads();
  if (t < 16) {
    float tot = 0.f;
#pragma unroll
    for (int c = 0; c < 16; c++) tot += part[c * 16 + t];
    rstdq[t] = rsqrtf(tot * (1.f / 128.f) + 1e-6f);
  }
  __syncthreads();
  {
    float rs = rstdq[h];
    s8v ov;
#pragma unroll
    for (int p = 0; p < 4; p++) {
      int d0 = ch * 8 + p * 2;
      float v0 = qv[p * 2]     * rs * rms_w[d0];
      float v1 = qv[p * 2 + 1] * rs * rms_w[d0 + 1];
      float cs = lcos[d0 >> 1], sn = lsin[d0 >> 1];
      ov[p * 2]     = (short)f2b((v0 * cs - v1 * sn) * 0.08838834764831845f);
      ov[p * 2 + 1] = (short)f2b((v0 * sn + v1 * cs) * 0.08838834764831845f);
    }
    *(s8v*)(qq + ((size_t)(b * 16 + h) * SQ + s) * HD_ + ch * 8) = ov;
  }
  __syncthreads();
  // ---- K/V (threads < 128) ----
  int kv = t & 7, ch2 = t >> 3;
  float kvs[8]; float ssk = 0.f;
  if (t < 128) {
#pragma unroll
    for (int j = 0; j < 8; j++) {
      float v = b2f(kr[(ch2 * 8 + j) * 8 + kv]);
      kvs[j] = v; ssk += v * v;
    }
    part[t] = ssk;
  }
  __syncthreads();
  if (t < 8) {
    float tot = 0.f;
#pragma unroll
    for (int c = 0; c < 16; c++) tot += part[c * 8 + t];
    rstdk[t] = rsqrtf(tot * (1.f / 128.f) + 1e-6f);
  }
  __syncthreads();
  if (t < 128) {
    float rs = rstdk[kv];
    s8v ov;
#pragma unroll
    for (int p = 0; p < 4; p++) {
      int d0 = ch2 * 8 + p * 2;
      float v0 = kvs[p * 2]     * rs * rms_w[d0];
      float v1 = kvs[p * 2 + 1] * rs * rms_w[d0 + 1];
      float cs = lcos[d0 >> 1], sn = lsin[d0 >> 1];
      ov[p * 2]     = (short)f2b(v0 * cs - v1 * sn);
      ov[p * 2 + 1] = (short)f2b(v0 * sn + v1 * cs);
    }
    *(s8v*)(kko + ((size_t)(b * 8 + kv) * SQ + s) * HD_ + ch2 * 8) = ov;
#pragma unroll
    for (int j = 0; j < 8; j++) {
      int d = ch2 * 8 + j;
      vto[((size_t)(b * 8 + kv) * HD_ + d) * SQ + s] = vr[d * 8 + kv];
    }
  }
}

// ---------------- causal flash attention v4: swapped QK^T, in-register softmax ----
// 32 Q rows/wave, S^T = mfma(K,Q): lane holds 8 scores for ONE query col s.
// Softmax: in-lane reduce + 2 shfl (masks 16,32). P->PV operand handoff via
// 8-shfl register exchange per group. O accumulated transposed (O^T[d][s]).
// No LDS, no lgkm drains in the loop.
__global__ __launch_bounds__(256, 2) void k_attn(const u16* __restrict__ qq,
                                                 const u16* __restrict__ kk,
                                                 const u16* __restrict__ vt,
                                                 u16* __restrict__ ctx) {
  const int tile = (blockIdx.z == 1) ? (15 - (int)blockIdx.x) : (int)blockIdx.x;
  const int s0 = tile * 128;
  const int h  = blockIdx.y;
  const int b  = blockIdx.z;
  const int kvh = h >> 1;
  const int tid = threadIdx.x, lane = tid & 63, w = tid >> 6;
  const int l15 = lane & 15, l4 = lane >> 4;
  const u16* qbase = qq + (size_t)(b * 16 + h) * SQ * HD_;
  const u16* kbase = kk + (size_t)(b * 8 + kvh) * SQ * HD_;
  const u16* vbase = vt + (size_t)(b * 8 + kvh) * HD_ * SQ;
  const int sw = s0 + w * 32;

  s8v qf[2][4];
#pragma unroll
  for (int g = 0; g < 2; g++)
#pragma unroll
    for (int c = 0; c < 4; c++)
      qf[g][c] = *(const s8v*)(qbase + (size_t)(sw + g * 16 + l15) * HD_ + c * 32 + l4 * 8);

  f4v o[2][8] = {};          // O^T: d = dd*16 + l4*4 + r, s = g*16 + l15
  float m2[2] = {-1e30f, -1e30f};
  float l2[2] = {0.f, 0.f};

  s8v kf[2][4], vf[8];
#pragma unroll
  for (int tt = 0; tt < 2; tt++)
#pragma unroll
    for (int c = 0; c < 4; c++)
      kf[tt][c] = *(const s8v*)(kbase + (size_t)(tt * 16 + l15) * HD_ + c * 32 + l4 * 8);
#pragma unroll
  for (int dd = 0; dd < 8; dd++)
    vf[dd] = *(const s8v*)(vbase + (size_t)(dd * 16 + l15) * SQ + l4 * 8);

  const int src1 = ((l4 & 1) << 5) + l15;   // P-exchange source lanes
  const int src2 = src1 + 16;
  const bool lo = (l4 < 2);

  const int bound = sw + 32;
  for (int t0 = 0; t0 < bound; t0 += 32) {
    // swapped QK^T: sc[tt][g] = S^T tile (row=t, col=s)
    f4v sc[2][2] = {};
    __builtin_amdgcn_s_setprio(1);
#pragma unroll
    for (int tt = 0; tt < 2; tt++)
#pragma unroll
      for (int g = 0; g < 2; g++)
#pragma unroll
        for (int c = 0; c < 4; c++)
          sc[tt][g] = __builtin_amdgcn_mfma_f32_16x16x32_bf16(kf[tt][c], qf[g][c], sc[tt][g], 0, 0, 0);
    __builtin_amdgcn_s_setprio(0);
    // reload kf for next tile (hides under softmax + PV)
    const int tn = (t0 + 32 < bound) ? (t0 + 32) : 0;
#pragma unroll
    for (int tt = 0; tt < 2; tt++)
#pragma unroll
      for (int c = 0; c < 4; c++)
        kf[tt][c] = *(const s8v*)(kbase + (size_t)(tn + tt * 16 + l15) * HD_ + c * 32 + l4 * 8);
    // causal mask — only the diagonal (last) iteration
    if (t0 >= sw) {
#pragma unroll
      for (int tt = 0; tt < 2; tt++)
#pragma unroll
        for (int g = 0; g < 2; g++)
#pragma unroll
          for (int r = 0; r < 4; r++) {
            int tg = t0 + tt * 16 + l4 * 4 + r;
            int sg = sw + g * 16 + l15;
            if (tg > sg) sc[tt][g][r] = -1e30f;
          }
    }
    // softmax (per group; each lane owns one column s)
    s8v pfg[2];
#pragma unroll
    for (int g = 0; g < 2; g++) {
      float mx = fmaxf(fmaxf(fmaxf(sc[0][g][0], sc[0][g][1]), fmaxf(sc[0][g][2], sc[0][g][3])),
                       fmaxf(fmaxf(sc[1][g][0], sc[1][g][1]), fmaxf(sc[1][g][2], sc[1][g][3])));
      mx = fmaxf(mx, __shfl_xor(mx, 16));
      mx = fmaxf(mx, __shfl_xor(mx, 32));
      if (__any(mx > m2[g] + 8.f)) {          // T13 defer-max
        float mn = fmaxf(m2[g], mx);
        float sf = exp2f((m2[g] - mn) * 1.44269504f);
        m2[g] = mn; l2[g] *= sf;
#pragma unroll
        for (int dd = 0; dd < 8; dd++)
#pragma unroll
          for (int r = 0; r < 4; r++) o[g][dd][r] *= sf;
      }
      float p0[4], p1[4], sum = 0.f;
#pragma unroll
      for (int r = 0; r < 4; r++) {
        p0[r] = exp2f((sc[0][g][r] - m2[g]) * 1.44269504f);
        p1[r] = exp2f((sc[1][g][r] - m2[g]) * 1.44269504f);
        sum += p0[r] + p1[r];
      }
      sum += __shfl_xor(sum, 16);
      sum += __shfl_xor(sum, 32);
      l2[g] += sum;
      // pack P^T pairs and exchange into PV B-fragment (k = t = l4*8 + j)
      u32 pa = pk2(p0[0], p0[1]), pb = pk2(p0[2], p0[3]);
      u32 pc = pk2(p1[0], p1[1]), pd = pk2(p1[2], p1[3]);
      u32 xa1 = (u32)__shfl((int)pa, src1), xc1 = (u32)__shfl((int)pc, src1);
      u32 xb1 = (u32)__shfl((int)pb, src1), xd1 = (u32)__shfl((int)pd, src1);
      u32 xa2 = (u32)__shfl((int)pa, src2), xc2 = (u32)__shfl((int)pc, src2);
      u32 xb2 = (u32)__shfl((int)pb, src2), xd2 = (u32)__shfl((int)pd, src2);
      u4v fr;
      fr[0] = lo ? xa1 : xc1;
      fr[1] = lo ? xb1 : xd1;
      fr[2] = lo ? xa2 : xc2;
      fr[3] = lo ? xb2 : xd2;
      pfg[g] = __builtin_bit_cast(s8v, fr);
    }
    // PV: O^T += V^T * P   (A = vf, B = pfg)
    __builtin_amdgcn_s_setprio(1);
#pragma unroll
    for (int dd = 0; dd < 8; dd++) {
      o[0][dd] = __builtin_amdgcn_mfma_f32_16x16x32_bf16(vf[dd], pfg[0], o[0][dd], 0, 0, 0);
      o[1][dd] = __builtin_amdgcn_mfma_f32_16x16x32_bf16(vf[dd], pfg[1], o[1][dd], 0, 0, 0);
    }
    __builtin_amdgcn_s_setprio(0);
    // reload vf for next tile (hides under next QK + softmax)
#pragma unroll
    for (int dd = 0; dd < 8; dd++)
      vf[dd] = *(const s8v*)(vbase + (size_t)(dd * 16 + l15) * SQ + tn + l4 * 8);
  }
  // epilogue: lane owns column s = sw + g*16 + l15; d = dd*16 + l4*4 + r
#pragma unroll
  for (int g = 0; g < 2; g++) {
    float inv = 1.f / l2[g];
    size_t rowoff = ((size_t)(b * SQ + sw + g * 16 + l15)) * HDIM + h * HD_;
#pragma unroll
    for (int dd = 0; dd < 8; dd++) {
      u32 w0 = pk2(o[g][dd][0] * inv, o[g][dd][1] * inv);
      u32 w1 = pk2(o[g][dd][2] * inv, o[g][dd][3] * inv);
      *(u32*)(ctx + rowoff + dd * 16 + l4 * 4)     = w0;
      *(u32*)(ctx + rowoff + dd * 16 + l4 * 4 + 2) = w1;
    }
  }
}

extern "C" void kernel_launch(void* const* d_in, const int* in_sizes, int n_in,
                              void* d_out, int out_size, void* d_ws, size_t ws_size,
                              hipStream_t stream) {
  const float* x     = (const float*)d_in[0];
  const float* wq    = (const float*)d_in[1];
  const float* wk    = (const float*)d_in[2];
  const float* wv    = (const float*)d_in[3];
  const float* wo    = (const float*)d_in[4];
  const float* rms_w = (const float*)d_in[5];
  const int*   pos   = (const int*)d_in[6];

  u16* w = (u16*)d_ws;
  u16* xb   = w;                    // 8388608  x bf16 [4096,2048]; later reused as ctx
  u16* wqt  = xb   + 8388608;       // 4194304  wq^T  — wqt/wkt/wvt contiguous = QKV B^T [4096][2048]
  u16* wkt  = wqt  + 4194304;       // 2097152
  u16* wvt  = wkt  + 2097152;       // 2097152
  u16* wot  = wvt  + 2097152;       // 4194304
  u16* qkvraw = wot + 4194304;      // 16777216 fused QKV GEMM out [4096][4096]
  u16* kkb  = qkvraw + 16777216;    // 4194304  kk[b,kv,s,d]
  u16* vtb  = kkb  + 4194304;       // 4194304  vt[b,kv,d,s]
  u16* qqb  = wqt;                  // alias over wqt..wvt (dead after QKV gemm)
  u16* ctxb = xb;                   // alias over xb (dead after gemms)

  k_cast<<<8192, 256, 0, stream>>>(x, xb, 2097152);
  k_transpose_cast<<<dim3(64, 64), dim3(32, 8), 0, stream>>>(wq, wqt, 2048, 2048);
  k_transpose_cast<<<dim3(32, 64), dim3(32, 8), 0, stream>>>(wk, wkt, 2048, 1024);
  k_transpose_cast<<<dim3(32, 64), dim3(32, 8), 0, stream>>>(wv, wvt, 2048, 1024);
  k_transpose_cast<<<dim3(64, 64), dim3(32, 8), 0, stream>>>(wo, wot, 2048, 2048);

  // fused QKV projection: [4096,2048] x [2048,4096] -> [4096,4096]
  k_gemm<0><<<dim3(32, 32), 256, 0, stream>>>(xb, wqt, qkvraw, 4096, 4096, 2048);

  k_normrope<<<4096, 256, 0, stream>>>(qkvraw, rms_w, pos, qqb, kkb, vtb);

  k_attn<<<dim3(16, 16, 2), 256, 0, stream>>>(qqb, kkb, vtb, ctxb);

  k_gemm<1><<<dim3(16, 32), 256, 0, stream>>>(ctxb, wot, d_out, 4096, 2048, 2048);
}